// Round 2
// baseline (6063.557 us; speedup 1.0000x reference)
//
#include <hip/hip_runtime.h>
#include <hip/hip_bf16.h>

#define NN 100000      // nodes
#define NE 1600000     // edges
#define DIM 128        // feature dim (in = hidden = 128)
#define NG 512         // graphs

typedef __attribute__((ext_vector_type(8))) short bf16x8;
typedef __attribute__((ext_vector_type(4))) float f32x4;

__device__ inline short f2bf(float f) {
    union { __hip_bfloat16 h; short s; } u;
    u.h = __float2bfloat16(f);
    return u.s;
}

// swizzled element offset of W^T[c][k] in LDS (8-elem chunk XOR swizzle keeps
// ds_read_b128 at the conflict-free floor without padding)
__device__ inline int wt_off(int c, int k) {
    return c * DIM + ((((k >> 3) ^ (c & 15)) << 3) | (k & 7));
}

// ---------------------------------------------------------------------------
__global__ __launch_bounds__(256) void degree_kernel(const int* __restrict__ src,
                                                     const int* __restrict__ dst,
                                                     float* __restrict__ deg) {
    int e = blockIdx.x * 256 + threadIdx.x;
    if (e < NE) {
        atomicAdd(&deg[src[e]], 1.0f);
        atomicAdd(&deg[NN + dst[e]], 1.0f);
    }
}

__global__ __launch_bounds__(256) void norm_kernel(float* __restrict__ deg) {
    int i = blockIdx.x * 256 + threadIdx.x;
    if (i < 2 * NN) deg[i] = rsqrtf(fmaxf(deg[i], 1.0f));
}

// ---------------------------------------------------------------------------
// MFMA GEMM: Xout[n,:] = pre(Xin[n,:]) @ W   (W row-major [128,128] fp32)
// LAYER 1: pre = x * norm_src[n]
// LAYER 2: pre = relu(x * norm_dst[n] + bias) * norm_src[n]
// One 16-row tile per wave, 4 waves/block. bf16 MFMA 16x16x32, fp32 acc.
template <int LAYER>
__global__ __launch_bounds__(256) void gemm_mfma(
    const float* __restrict__ Xin, const float* __restrict__ norm_src,
    const float* __restrict__ norm_dst, const float* __restrict__ bias,
    const float* __restrict__ W, float* __restrict__ Xout) {
    __shared__ __hip_bfloat16 Wt[DIM * DIM];   // W^T, swizzled, 32 KB
    for (int idx = threadIdx.x; idx < DIM * DIM; idx += 256) {
        int k = idx >> 7, c = idx & 127;       // W[k][c], coalesced global read
        Wt[wt_off(c, k)] = __float2bfloat16(W[idx]);
    }
    __syncthreads();

    const int wave = threadIdx.x >> 6;
    const int lane = threadIdx.x & 63;
    const int tile = blockIdx.x * 4 + wave;    // 16-row output tile
    if (tile >= NN / 16) return;               // NN % 16 == 0
    const int row0 = tile * 16;
    const int lr = lane & 15;                  // A-row within tile / D-col within ntile
    const int q  = lane >> 4;                  // lane quad
    const int row = row0 + lr;

    // A fragments: afrag[kt] holds x[row][kt*32 + q*8 + j], j=0..7 (bf16)
    const float ns = norm_src[row];
    bf16x8 afrag[4];
#pragma unroll
    for (int kt = 0; kt < 4; kt++) {
        const int k0 = kt * 32 + q * 8;
        const float* p = Xin + row * DIM + k0;
        float v[8];
#pragma unroll
        for (int j = 0; j < 8; j++) v[j] = p[j];
        if (LAYER == 2) {
            const float nd = norm_dst[row];
#pragma unroll
            for (int j = 0; j < 8; j++)
                v[j] = fmaxf(v[j] * nd + bias[k0 + j], 0.0f);
        }
#pragma unroll
        for (int j = 0; j < 8; j++) ((short*)&afrag[kt])[j] = f2bf(v[j] * ns);
    }

#pragma unroll
    for (int nt = 0; nt < 8; nt++) {
        f32x4 acc = {0.f, 0.f, 0.f, 0.f};
        const int c = nt * 16 + lr;
#pragma unroll
        for (int kt = 0; kt < 4; kt++) {
            const int k0 = kt * 32 + q * 8;
            bf16x8 b = *(const bf16x8*)&Wt[wt_off(c, k0)];
            acc = __builtin_amdgcn_mfma_f32_16x16x32_bf16(afrag[kt], b, acc, 0, 0, 0);
        }
        // D layout: col = lane&15, row = q*4 + reg  [m89-verified]
#pragma unroll
        for (int r = 0; r < 4; r++)
            Xout[(row0 + q * 4 + r) * DIM + c] = acc[r];
    }
}

// ---------------------------------------------------------------------------
// Edge scatter: AGG[dst[e],:] += X[src[e],:]   (32 threads/edge, float4)
__global__ __launch_bounds__(256) void scatter_kernel(
    const int* __restrict__ src, const int* __restrict__ dst,
    const float* __restrict__ X, float* __restrict__ AGG) {
    int idx = blockIdx.x * 256 + threadIdx.x;   // NE*32 = 51.2M threads
    int e = idx >> 5;
    int jj = (idx & 31) * 4;
    int s = src[e], d = dst[e];
    f32x4 v = *(const f32x4*)&X[s * DIM + jj];
    float* a = &AGG[d * DIM + jj];
    atomicAdd(a + 0, v.x);
    atomicAdd(a + 1, v.y);
    atomicAdd(a + 2, v.z);
    atomicAdd(a + 3, v.w);
}

// ---------------------------------------------------------------------------
// Readout: sums[g,:] += relu(AGG[n,:]*norm_dst[n] + b2); counts[g] += 1
__global__ __launch_bounds__(256) void readout_kernel(
    const float* __restrict__ AGG, const float* __restrict__ norm_dst,
    const float* __restrict__ b2, const int* __restrict__ gids,
    float* __restrict__ sums, float* __restrict__ counts) {
    int idx = blockIdx.x * 256 + threadIdx.x;   // NN*32 threads exactly
    int n = idx >> 5;
    int jj = (idx & 31) * 4;
    float nd = norm_dst[n];
    int g = gids[n];
    f32x4 v = *(const f32x4*)&AGG[n * DIM + jj];
    float* s = &sums[g * DIM + jj];
    atomicAdd(s + 0, fmaxf(v.x * nd + b2[jj + 0], 0.0f));
    atomicAdd(s + 1, fmaxf(v.y * nd + b2[jj + 1], 0.0f));
    atomicAdd(s + 2, fmaxf(v.z * nd + b2[jj + 2], 0.0f));
    atomicAdd(s + 3, fmaxf(v.w * nd + b2[jj + 3], 0.0f));
    if (jj == 0) atomicAdd(&counts[g], 1.0f);
}

// out[g] = dot(sums[g,:], W3)/max(counts[g],1) + b3   (one wave per graph)
__global__ __launch_bounds__(64) void final_kernel(
    const float* __restrict__ sums, const float* __restrict__ counts,
    const float* __restrict__ W3, const float* __restrict__ b3,
    float* __restrict__ out) {
    int g = blockIdx.x, t = threadIdx.x;
    float acc = sums[g * DIM + t] * W3[t] + sums[g * DIM + t + 64] * W3[t + 64];
#pragma unroll
    for (int off = 32; off; off >>= 1) acc += __shfl_down(acc, off);
    if (t == 0) out[g] = acc / fmaxf(counts[g], 1.0f) + b3[0];
}

// ---------------------------------------------------------------------------
extern "C" void kernel_launch(void* const* d_in, const int* in_sizes, int n_in,
                              void* d_out, int out_size, void* d_ws, size_t ws_size,
                              hipStream_t stream) {
    const float* h   = (const float*)d_in[0];
    const int* src   = (const int*)d_in[1];
    const int* dst   = (const int*)d_in[2];
    const int* gids  = (const int*)d_in[3];
    // d_in[4] = num_graphs scalar (fixed 512)
    const float* W1  = (const float*)d_in[5];
    const float* b1  = (const float*)d_in[6];
    const float* W2  = (const float*)d_in[7];
    const float* b2  = (const float*)d_in[8];
    const float* W3  = (const float*)d_in[9];
    const float* b3  = (const float*)d_in[10];

    // workspace layout (256B-aligned offsets)
    const size_t OFF_X    = 800000;                       // after deg (2*NN fp32)
    const size_t OFF_AGG  = OFF_X + 51200000;             // NN*DIM fp32
    const size_t OFF_SUM  = OFF_AGG + 51200000;           // NG*DIM fp32
    const size_t OFF_CNT  = OFF_SUM + 262144;             // NG fp32
    const size_t REQUIRED = OFF_CNT + 2048;               // ~103.5 MB
    if (ws_size < REQUIRED) {                             // diagnosable fallback
        hipMemsetAsync(d_out, 0, out_size * sizeof(float), stream);
        return;
    }
    char* ws = (char*)d_ws;
    float* deg      = (float*)ws;
    float* norm_src = deg;
    float* norm_dst = deg + NN;
    float* X        = (float*)(ws + OFF_X);
    float* AGG      = (float*)(ws + OFF_AGG);
    float* sums     = (float*)(ws + OFF_SUM);
    float* counts   = (float*)(ws + OFF_CNT);

    // 1. degrees -> norms
    hipMemsetAsync(deg, 0, 2 * NN * sizeof(float), stream);
    degree_kernel<<<(NE + 255) / 256, 256, 0, stream>>>(src, dst, deg);
    norm_kernel<<<(2 * NN + 255) / 256, 256, 0, stream>>>(deg);

    const int gemm_grid = (NN / 16 + 3) / 4;   // 4 tiles (waves) per block

    // 2. layer 1: project (MFMA), scatter
    gemm_mfma<1><<<gemm_grid, 256, 0, stream>>>(h, norm_src, norm_dst, b1, W1, X);
    hipMemsetAsync(AGG, 0, (size_t)NN * DIM * sizeof(float), stream);
    scatter_kernel<<<(NE * 32) / 256, 256, 0, stream>>>(src, dst, X, AGG);

    // 3. layer 2: fused relu/norm pre-op + project, scatter
    gemm_mfma<2><<<gemm_grid, 256, 0, stream>>>(AGG, norm_src, norm_dst, b1, W2, X);
    hipMemsetAsync(AGG, 0, (size_t)NN * DIM * sizeof(float), stream);
    scatter_kernel<<<(NE * 32) / 256, 256, 0, stream>>>(src, dst, X, AGG);

    // 4. readout + final linear
    hipMemsetAsync(sums, 0, (NG * DIM + NG) * sizeof(float), stream);
    readout_kernel<<<(NN * 32) / 256, 256, 0, stream>>>(AGG, norm_dst, b2, gids,
                                                        sums, counts);
    final_kernel<<<NG, 64, 0, stream>>>(sums, counts, W3, b3, (float*)d_out);
}

// Round 3
// 582.076 us; speedup vs baseline: 10.4171x; 10.4171x over previous
//
#include <hip/hip_runtime.h>
#include <hip/hip_bf16.h>

#define NN 100000      // nodes
#define NE 1600000     // edges
#define DIM 128        // feature dim
#define NG 512         // graphs
#define NB 391         // scan blocks = ceil(NN/256)

typedef __attribute__((ext_vector_type(8))) short bf16x8;
typedef __attribute__((ext_vector_type(4))) float f32x4;
typedef __attribute__((ext_vector_type(2))) float f32x2;

__device__ inline short f2bf(float f) {
    union { __hip_bfloat16 h; short s; } u;
    u.h = __float2bfloat16(f);
    return u.s;
}

// swizzled element offset of W^T[c][k] in LDS
__device__ inline int wt_off(int c, int k) {
    return c * DIM + ((((k >> 3) ^ (c & 15)) << 3) | (k & 7));
}

// ---------------------------------------------------------------------------
// degree histograms (int atomics)
__global__ __launch_bounds__(256) void hist_kernel(const int* __restrict__ src,
                                                   const int* __restrict__ dst,
                                                   int* __restrict__ cin,
                                                   int* __restrict__ cout) {
    int e = blockIdx.x * 256 + threadIdx.x;
    if (e < NE) {
        atomicAdd(&cin[dst[e]], 1);
        atomicAdd(&cout[src[e]], 1);
    }
}

// norms from integer degrees
__global__ __launch_bounds__(256) void norm_kernel(const int* __restrict__ cin,
                                                   const int* __restrict__ cout,
                                                   float* __restrict__ norm_src,
                                                   float* __restrict__ norm_dst) {
    int i = blockIdx.x * 256 + threadIdx.x;
    if (i < NN) {
        norm_src[i] = rsqrtf((float)max(cout[i], 1));
        norm_dst[i] = rsqrtf((float)max(cin[i], 1));
    }
}

// ---------------------------------------------------------------------------
// exclusive scan of cin -> row_start  (3-kernel 2-level scan)
__global__ __launch_bounds__(256) void scan1_kernel(const int* __restrict__ cin,
                                                    int* __restrict__ row,
                                                    int* __restrict__ bsum) {
    __shared__ int t[256];
    int i = blockIdx.x * 256 + threadIdx.x;
    int v = (i < NN) ? cin[i] : 0;
    t[threadIdx.x] = v;
    __syncthreads();
    for (int off = 1; off < 256; off <<= 1) {
        int x = (threadIdx.x >= off) ? t[threadIdx.x - off] : 0;
        __syncthreads();
        t[threadIdx.x] += x;
        __syncthreads();
    }
    if (i < NN) row[i] = t[threadIdx.x] - v;          // exclusive
    if (threadIdx.x == 255) bsum[blockIdx.x] = t[255];
}

__global__ __launch_bounds__(512) void scan2_kernel(int* __restrict__ bsum) {
    __shared__ int t[512];
    int v = (threadIdx.x < NB) ? bsum[threadIdx.x] : 0;
    t[threadIdx.x] = v;
    __syncthreads();
    for (int off = 1; off < 512; off <<= 1) {
        int x = (threadIdx.x >= off) ? t[threadIdx.x - off] : 0;
        __syncthreads();
        t[threadIdx.x] += x;
        __syncthreads();
    }
    if (threadIdx.x < NB) bsum[threadIdx.x] = t[threadIdx.x] - v;  // exclusive
}

__global__ __launch_bounds__(256) void scan3_kernel(int* __restrict__ row,
                                                    const int* __restrict__ bsum) {
    int i = blockIdx.x * 256 + threadIdx.x;
    if (i < NN) row[i] += bsum[i >> 8];
    if (i == 0) row[NN] = NE;
}

// fill CSR: esrc[pos] = src, sorted by dst
__global__ __launch_bounds__(256) void fill_kernel(const int* __restrict__ src,
                                                   const int* __restrict__ dst,
                                                   int* __restrict__ cursor,
                                                   int* __restrict__ esrc) {
    int e = blockIdx.x * 256 + threadIdx.x;
    if (e < NE) {
        int pos = atomicAdd(&cursor[dst[e]], 1);
        esrc[pos] = src[e];
    }
}

// graph start offsets: gstart[g] = lower_bound(gids, g), g in [0, NG]
__global__ __launch_bounds__(256) void gstart_kernel(const int* __restrict__ gids,
                                                     int* __restrict__ gstart) {
    int g = blockIdx.x * 256 + threadIdx.x;
    if (g > NG) return;
    int lo = 0, hi = NN;
    while (lo < hi) {
        int mid = (lo + hi) >> 1;
        if (gids[mid] < g) lo = mid + 1; else hi = mid;
    }
    gstart[g] = lo;
}

// ---------------------------------------------------------------------------
// MFMA GEMM: Xout(bf16)[n,:] = pre(Xin[n,:]) @ W
// LAYER 1: pre = x * ns      LAYER 2: pre = relu(x*nd + bias) * ns
template <int LAYER>
__global__ __launch_bounds__(256) void gemm_mfma(
    const float* __restrict__ Xin, const float* __restrict__ norm_src,
    const float* __restrict__ norm_dst, const float* __restrict__ bias,
    const float* __restrict__ W, __hip_bfloat16* __restrict__ Xout) {
    __shared__ __hip_bfloat16 Wt[DIM * DIM];
    for (int idx = threadIdx.x; idx < DIM * DIM; idx += 256) {
        int k = idx >> 7, c = idx & 127;
        Wt[wt_off(c, k)] = __float2bfloat16(W[idx]);
    }
    __syncthreads();

    const int wave = threadIdx.x >> 6;
    const int lane = threadIdx.x & 63;
    const int tile = blockIdx.x * 4 + wave;
    if (tile >= NN / 16) return;
    const int row0 = tile * 16;
    const int lr = lane & 15;
    const int q  = lane >> 4;
    const int row = row0 + lr;

    const float ns = norm_src[row];
    bf16x8 afrag[4];
#pragma unroll
    for (int kt = 0; kt < 4; kt++) {
        const int k0 = kt * 32 + q * 8;
        const float* p = Xin + row * DIM + k0;
        float v[8];
#pragma unroll
        for (int j = 0; j < 8; j++) v[j] = p[j];
        if (LAYER == 2) {
            const float nd = norm_dst[row];
#pragma unroll
            for (int j = 0; j < 8; j++)
                v[j] = fmaxf(v[j] * nd + bias[k0 + j], 0.0f);
        }
#pragma unroll
        for (int j = 0; j < 8; j++) ((short*)&afrag[kt])[j] = f2bf(v[j] * ns);
    }

#pragma unroll
    for (int nt = 0; nt < 8; nt++) {
        f32x4 acc = {0.f, 0.f, 0.f, 0.f};
        const int c = nt * 16 + lr;
#pragma unroll
        for (int kt = 0; kt < 4; kt++) {
            const int k0 = kt * 32 + q * 8;
            bf16x8 b = *(const bf16x8*)&Wt[wt_off(c, k0)];
            acc = __builtin_amdgcn_mfma_f32_16x16x32_bf16(afrag[kt], b, acc, 0, 0, 0);
        }
#pragma unroll
        for (int r = 0; r < 4; r++)
            Xout[(row0 + q * 4 + r) * DIM + c] = __float2bfloat16(acc[r]);
    }
}

// ---------------------------------------------------------------------------
// CSR gather: AGG[n,:] = sum_{e in in(n)} X[esrc[e],:]   (one wave per node)
// X viewed as uint rows of 64 dwords (2 bf16 per lane).
__global__ __launch_bounds__(256) void gather_kernel(
    const int* __restrict__ row, const int* __restrict__ esrc,
    const unsigned int* __restrict__ Xb, float* __restrict__ AGG) {
    int wid = (blockIdx.x * 256 + threadIdx.x) >> 6;   // node; grid gives exactly NN
    int lane = threadIdx.x & 63;
    int s0 = row[wid], s1 = row[wid + 1];
    float ax = 0.f, ay = 0.f;
    int e = s0;
    for (; e + 4 <= s1; e += 4) {
        int i0 = esrc[e], i1 = esrc[e + 1], i2 = esrc[e + 2], i3 = esrc[e + 3];
        unsigned int u0 = Xb[i0 * 64 + lane];
        unsigned int u1 = Xb[i1 * 64 + lane];
        unsigned int u2 = Xb[i2 * 64 + lane];
        unsigned int u3 = Xb[i3 * 64 + lane];
        ax += __uint_as_float(u0 << 16) + __uint_as_float(u1 << 16)
            + __uint_as_float(u2 << 16) + __uint_as_float(u3 << 16);
        ay += __uint_as_float(u0 & 0xffff0000u) + __uint_as_float(u1 & 0xffff0000u)
            + __uint_as_float(u2 & 0xffff0000u) + __uint_as_float(u3 & 0xffff0000u);
    }
    for (; e < s1; e++) {
        unsigned int u = Xb[esrc[e] * 64 + lane];
        ax += __uint_as_float(u << 16);
        ay += __uint_as_float(u & 0xffff0000u);
    }
    f32x2 out = {ax, ay};
    *(f32x2*)&AGG[wid * DIM + lane * 2] = out;
}

// ---------------------------------------------------------------------------
// fused readout: out[g] = (sum_{n in g} sum_j relu(AGG[n,j]*nd[n]+b2[j])*W3[j])
//                         / max(cnt,1) + b3      (one block per graph)
__global__ __launch_bounds__(256) void readout_kernel(
    const float* __restrict__ AGG, const float* __restrict__ norm_dst,
    const float* __restrict__ b2, const int* __restrict__ gstart,
    const float* __restrict__ W3, const float* __restrict__ b3,
    float* __restrict__ out) {
    int g = blockIdx.x;
    int s = gstart[g], t = gstart[g + 1];
    int j = threadIdx.x & 127, half = threadIdx.x >> 7;
    float w = W3[j], bj = b2[j];
    float acc = 0.f;
    for (int n = s + half; n < t; n += 2) {
        float v = fmaxf(AGG[n * DIM + j] * norm_dst[n] + bj, 0.0f);
        acc += v * w;
    }
#pragma unroll
    for (int off = 32; off; off >>= 1) acc += __shfl_down(acc, off);
    __shared__ float red[4];
    if ((threadIdx.x & 63) == 0) red[threadIdx.x >> 6] = acc;
    __syncthreads();
    if (threadIdx.x == 0) {
        float total = red[0] + red[1] + red[2] + red[3];
        out[g] = total / fmaxf((float)(t - s), 1.0f) + b3[0];
    }
}

// ---------------------------------------------------------------------------
extern "C" void kernel_launch(void* const* d_in, const int* in_sizes, int n_in,
                              void* d_out, int out_size, void* d_ws, size_t ws_size,
                              hipStream_t stream) {
    const float* h   = (const float*)d_in[0];
    const int* src   = (const int*)d_in[1];
    const int* dst   = (const int*)d_in[2];
    const int* gids  = (const int*)d_in[3];
    const float* W1  = (const float*)d_in[5];
    const float* b1  = (const float*)d_in[6];
    const float* W2  = (const float*)d_in[7];
    const float* b2  = (const float*)d_in[8];
    const float* W3  = (const float*)d_in[9];
    const float* b3  = (const float*)d_in[10];

    // workspace layout (256B-aligned)
    const size_t OFF_NRM  = 0;                          // 2*NN fp32
    const size_t OFF_CIN  = OFF_NRM + 800256;           // NN int
    const size_t OFF_COUT = OFF_CIN + 400384;           // NN int
    const size_t OFF_ROW  = OFF_COUT + 400384;          // NN+1 int
    const size_t OFF_CUR  = OFF_ROW + 400640;           // NN+1 int
    const size_t OFF_BSUM = OFF_CUR + 400640;           // NB int
    const size_t OFF_GST  = OFF_BSUM + 2048;            // NG+1 int
    const size_t OFF_ESRC = OFF_GST + 2304;             // NE int
    const size_t OFF_X    = OFF_ESRC + 6400256;         // NN*DIM bf16
    const size_t OFF_AGG  = OFF_X + 25600000;           // NN*DIM fp32
    const size_t REQUIRED = OFF_AGG + 51200000;         // ~85.6 MB
    if (ws_size < REQUIRED) {
        hipMemsetAsync(d_out, 0, out_size * sizeof(float), stream);
        return;
    }
    char* ws = (char*)d_ws;
    float* norm_src = (float*)(ws + OFF_NRM);
    float* norm_dst = norm_src + NN;
    int*   cin      = (int*)(ws + OFF_CIN);
    int*   cout_    = (int*)(ws + OFF_COUT);
    int*   row      = (int*)(ws + OFF_ROW);
    int*   cursor   = (int*)(ws + OFF_CUR);
    int*   bsum     = (int*)(ws + OFF_BSUM);
    int*   gstart   = (int*)(ws + OFF_GST);
    int*   esrc     = (int*)(ws + OFF_ESRC);
    __hip_bfloat16* X = (__hip_bfloat16*)(ws + OFF_X);
    unsigned int*  Xb = (unsigned int*)(ws + OFF_X);
    float* AGG      = (float*)(ws + OFF_AGG);

    // 1. CSR build + norms
    hipMemsetAsync(cin, 0, 2 * 400384, stream);         // cin + cout (contiguous)
    hist_kernel<<<(NE + 255) / 256, 256, 0, stream>>>(src, dst, cin, cout_);
    norm_kernel<<<(NN + 255) / 256, 256, 0, stream>>>(cin, cout_, norm_src, norm_dst);
    scan1_kernel<<<NB, 256, 0, stream>>>(cin, row, bsum);
    scan2_kernel<<<1, 512, 0, stream>>>(bsum);
    scan3_kernel<<<NB, 256, 0, stream>>>(row, bsum);
    hipMemcpyAsync(cursor, row, NN * sizeof(int), hipMemcpyDeviceToDevice, stream);
    fill_kernel<<<(NE + 255) / 256, 256, 0, stream>>>(src, dst, cursor, esrc);
    gstart_kernel<<<3, 256, 0, stream>>>(gids, gstart);

    const int gemm_grid = (NN / 16 + 3) / 4;

    // 2. layer 1: project (MFMA, bf16 out), CSR gather
    gemm_mfma<1><<<gemm_grid, 256, 0, stream>>>(h, norm_src, norm_dst, b1, W1, X);
    gather_kernel<<<NN / 4, 256, 0, stream>>>(row, esrc, Xb, AGG);

    // 3. layer 2: fused relu/norm pre-op + project, CSR gather
    gemm_mfma<2><<<gemm_grid, 256, 0, stream>>>(AGG, norm_src, norm_dst, b1, W2, X);
    gather_kernel<<<NN / 4, 256, 0, stream>>>(row, esrc, Xb, AGG);

    // 4. fused per-graph mean + final linear
    readout_kernel<<<NG, 256, 0, stream>>>(AGG, norm_dst, b2, gstart, W3, b3,
                                           (float*)d_out);
}